// Round 3
// baseline (2787.984 us; speedup 1.0000x reference)
//
#include <hip/hip_runtime.h>

#define DEV __device__ __forceinline__

typedef float f32x4 __attribute__((ext_vector_type(4)));
typedef short s16x8 __attribute__((ext_vector_type(8)));
typedef short s16x4 __attribute__((ext_vector_type(4)));

// ---------- scalar helpers ----------
DEV unsigned short f2bf(float f){
  unsigned int u = __float_as_uint(f);
  u += 0x7fffu + ((u>>16)&1u);
  return (unsigned short)(u>>16);
}
DEV float bf2f(unsigned short h){ return __uint_as_float(((unsigned int)h)<<16); }

#if __has_builtin(__builtin_amdgcn_rcpf)
DEV float frcp_(float x){ return __builtin_amdgcn_rcpf(x); }
#else
DEV float frcp_(float x){ return 1.f/x; }
#endif
#if __has_builtin(__builtin_amdgcn_exp2f)
DEV float fexp2_(float x){ return __builtin_amdgcn_exp2f(x); }
#else
DEV float fexp2_(float x){ return exp2f(x); }
#endif

DEV float tanh_(float x){
  x = fminf(x, 30.f);
  float e = fexp2_(2.8853900817779268f*x);
  return (e-1.f)*frcp_(e+1.f);
}

// branchless f32 -> OCP e4m3fn (fallback when no HW cvt)
DEV unsigned char f2e4m3(float x){
  unsigned int u = __float_as_uint(x);
  unsigned int s = (u>>24)&0x80u;
  unsigned int mag = u & 0x7fffffffu;
  if (mag > 0x43E00000u) mag = 0x43E00000u;
  mag += 0x000FFFFFu + ((mag>>20)&1u);
  int e = (int)(mag>>23) - 120;
  unsigned int m = (mag>>20)&7u;
  unsigned int r = (e<=0) ? 0u : (((unsigned)e<<3)|m);
  return (unsigned char)(s|r);
}

DEV f32x4 mfma_bf16(s16x8 a, s16x8 b, f32x4 c){
  return __builtin_amdgcn_mfma_f32_16x16x32_bf16(a,b,c,0,0,0);
}
DEV f32x4 mfma_fp8(long a, long b, f32x4 c){
  return __builtin_amdgcn_mfma_f32_16x16x32_fp8_fp8(a,b,c,0,0,0);
}

// LDS-only barrier (no vmcnt drain)
DEV void lds_barrier(){
  asm volatile("s_waitcnt lgkmcnt(0)\n\ts_barrier" ::: "memory");
}

// ---------- problem constants ----------
#define Bx 128
#define Vx 64
#define Sx 40
#define Dx 256
#define Hx 256
#define NVOC 20001

// d_out element offsets (f32)
#define OFF_OG   0
#define OFF_FAKE 256
#define OFF_DECV 512
#define OFF_GENV 2097664
#define OFF_STS  4194816
#define OFF_LBL  4203008

// bf16 weight-pool element offsets
#define PW_IH  0
#define PW_HH  262144
#define PW_HK  524288
#define PW_1   589824
#define PC_1   622592
#define PC_2   884736
#define PC_O   1409024
#define P_TOT  1410048

#define HPB 264      // scan LDS fp8 row pitch (bytes)
#define BFP 272      // bf16 LDS tile pitch (shorts)
#define XGP 20       // xg2T LDS pitch (shorts)

// ---------- K-1: emb f32 -> bf16 ----------
__global__ void k_cvt_emb(const float* __restrict__ emb, unsigned short* __restrict__ emb16){
  size_t i = (size_t)blockIdx.x*256 + threadIdx.x;
  emb16[i] = f2bf(emb[i]);
}

// ---------- PRE: embed + weight cvt + passthrough ----------
__global__ void k_pre(const int* __restrict__ seqs, const unsigned short* __restrict__ emb16,
                      unsigned short* __restrict__ v16,
                      float* __restrict__ decv, float* __restrict__ genv,
                      const float* __restrict__ W_ih, const float* __restrict__ Whh,
                      const float* __restrict__ Whk, const float* __restrict__ W1,
                      const float* __restrict__ C1W, const float* __restrict__ C2W,
                      const float* __restrict__ CoW,
                      unsigned short* __restrict__ pool, unsigned char* __restrict__ whh8,
                      const float* __restrict__ sts, const int* __restrict__ label,
                      float* __restrict__ out){
  int bx = blockIdx.x, tid = threadIdx.x;
  if (bx < 8192){                       // embed: v = sum_s relu(emb[idx])
    int bt = bx, d = tid;
    const int* sp = seqs + (size_t)bt*Sx;
    float acc = 0.f;
    #pragma unroll 8
    for (int s=0;s<Sx;s++) acc += fmaxf(bf2f(emb16[(size_t)sp[s]*Dx + d]), 0.f);
    size_t o = (size_t)bt*Dx + d;
    v16[o] = f2bf(acc);
    if ((bt & 63) == 0){ decv[o] = acc; genv[o] = acc; }
    return;
  }
  if (bx < 14724){                      // weight conversions
    int i = (bx-8192)*256 + tid;
    if (i < P_TOT){
      float v;
      if      (i < PW_HH) v = W_ih[i - PW_IH];
      else if (i < PW_HK) v = Whh [i - PW_HH];
      else if (i < PW_1 ) v = Whk [i - PW_HK];
      else if (i < PC_1 ) v = W1  [i - PW_1 ];
      else if (i < PC_2 ) v = C1W [i - PC_1 ];
      else if (i < PC_O ) v = C2W [i - PC_2 ];
      else                v = CoW [i - PC_O ];
      pool[i] = f2bf(v);
    } else if (i < P_TOT + 262144){
      whh8[i - P_TOT] = f2e4m3(16.f*Whh[i - P_TOT]);
    }
    return;
  }
  // misc block: passthrough outputs
  for (int i=tid;i<Bx*Vx;i+=256) out[OFF_STS + i] = sts[i];
  if (tid < Bx) out[OFF_LBL + tid] = (float)label[tid];
}

// ---------- generic MFMA GEMM (xg1 + classifier layers) ----------
template<int MODE_A, int MODE_C, int RELU>
__global__ void k_gemm(const unsigned short* __restrict__ A, const unsigned short* __restrict__ Bw,
                       const float* __restrict__ bias1, const float* __restrict__ bias2,
                       unsigned short* __restrict__ C, int K, int Ntot, float scale){
  int tid = threadIdx.x, w = tid>>6, l = tid&63, lm = l&15, q = l>>4;
  int m0 = blockIdx.x*64;
  int n0 = blockIdx.y*256 + w*64;
  f32x4 acc[4][4];
  #pragma unroll
  for (int nt=0;nt<4;nt++){
    int n = n0 + nt*16 + lm;
    float bz = bias1 ? bias1[n] : 0.f;
    if (bias2) bz += bias2[n];
    #pragma unroll
    for (int mt=0;mt<4;mt++) acc[mt][nt] = (f32x4){bz,bz,bz,bz};
  }
  const s16x8* Arow[4];
  #pragma unroll
  for (int mt=0;mt<4;mt++){
    int m = m0 + mt*16 + lm;
    size_t off = (MODE_A==0) ? (size_t)m*K : ((size_t)(m&127)*Vx + (m>>7))*(size_t)K;
    Arow[mt] = (const s16x8*)(A + off);
  }
  int kkn = K/32;
  for (int kk=0; kk<kkn; kk++){
    s16x8 bfr[4];
    #pragma unroll
    for (int nt=0;nt<4;nt++){
      int n = n0 + nt*16 + lm;
      bfr[nt] = *(const s16x8*)(Bw + (size_t)n*K + kk*32 + q*8);
    }
    #pragma unroll
    for (int mt=0;mt<4;mt++){
      s16x8 afr = Arow[mt][kk*4 + q];
      #pragma unroll
      for (int nt=0;nt<4;nt++)
        acc[mt][nt] = mfma_bf16(afr, bfr[nt], acc[mt][nt]);
    }
  }
  #pragma unroll
  for (int mt=0;mt<4;mt++){
    int mbase = m0 + mt*16 + q*4;
    #pragma unroll
    for (int nt=0;nt<4;nt++){
      int n = n0 + nt*16 + lm;
      if (MODE_C==0){
        #pragma unroll
        for (int r=0;r<4;r++){
          float val = scale*acc[mt][nt][r];
          if (RELU) val = fmaxf(val, 0.f);
          C[(size_t)(mbase+r)*Ntot + n] = f2bf(val);
        }
      } else {
        int tt = mbase>>7, bb = mbase&127;
        int gg = bb>>4;
        s16x4 sv;
        #pragma unroll
        for (int r=0;r<4;r++) sv[r] = (short)f2bf(scale*acc[mt][nt][r]);
        *(s16x4*)(C + (((size_t)tt*8 + gg)*1024 + n)*16 + (bb&15)) = sv;
      }
    }
  }
}

// ---------- LSTM gate activations (inputs scaled by 256) ----------
DEV void lstm_act(const f32x4* A, float* cst, float* hv){
  const float K1 = 1.4426950408889634f/256.f;
  #pragma unroll
  for (int r=0;r<4;r++){
    float iv = frcp_(1.f + fexp2_(-K1*A[0][r]));
    float fv = frcp_(1.f + fexp2_(-K1*A[1][r]));
    float eg = fexp2_(2.f*K1*A[2][r]);
    float gv = (eg-1.f)*frcp_(eg+1.f);
    float ov = frcp_(1.f + fexp2_(-K1*A[3][r]));
    float cv = fv*cst[r] + iv*gv;
    cst[r] = cv;
    float ec = fexp2_(2.8853900817779268f*fminf(cv,30.f));
    hv[r] = ov*(ec-1.f)*frcp_(ec+1.f);
  }
}

// store 4 h values (rows q*4+r) as fp8(16*h) at column j of next h-buffer
DEV void store_h_fp8(unsigned char* hn, int q, const float* hv){
#if __has_builtin(__builtin_amdgcn_cvt_pk_fp8_f32)
  int p01 = __builtin_amdgcn_cvt_pk_fp8_f32(16.f*hv[0], 16.f*hv[1], 0, false);
  int p23 = __builtin_amdgcn_cvt_pk_fp8_f32(16.f*hv[2], 16.f*hv[3], 0, false);
  hn[(q*4+0)*HPB] = (unsigned char)p01;
  hn[(q*4+1)*HPB] = (unsigned char)(p01>>8);
  hn[(q*4+2)*HPB] = (unsigned char)p23;
  hn[(q*4+3)*HPB] = (unsigned char)(p23>>8);
#else
  #pragma unroll
  for (int r=0;r<4;r++) hn[(q*4+r)*HPB] = f2e4m3(16.f*hv[r]);
#endif
}

// xg2 GEMM: xgT[n][row] = 256*(barv @ W_ih^T + b_ih + b_hh), wave w owns n in [w*64, w*64+64)
DEV void xg2_gemm(const unsigned short* bvl, const unsigned short* pool,
                  const float* __restrict__ b_ih, const float* __restrict__ b_hh,
                  unsigned short* xgT, int w, int lm, int q){
  f32x4 acc[4];
  #pragma unroll
  for (int nt=0;nt<4;nt++){
    int n = w*64 + nt*16 + lm;
    float bz = b_ih[n] + b_hh[n];
    acc[nt] = (f32x4){bz,bz,bz,bz};
  }
  #pragma unroll
  for (int kk=0;kk<8;kk++){
    s16x8 afr = *(const s16x8*)(bvl + lm*BFP + kk*32 + q*8);
    #pragma unroll
    for (int nt=0;nt<4;nt++){
      int n = w*64 + nt*16 + lm;
      s16x8 bfr = *(const s16x8*)(pool + PW_IH + (size_t)n*256 + kk*32 + q*8);
      acc[nt] = mfma_bf16(afr, bfr, acc[nt]);
    }
  }
  #pragma unroll
  for (int nt=0;nt<4;nt++){
    int n = w*64 + nt*16 + lm;
    s16x4 sv;
    #pragma unroll
    for (int r=0;r<4;r++) sv[r] = (short)f2bf(256.f*acc[nt][r]);
    *(s16x4*)(xgT + n*XGP + q*4) = sv;
  }
}

// ---------- MEGA: fully fused per-batch-group pipeline, zero inter-block sync ----------
// Block g owns batch rows [g*16, g*16+16). LDS-only per-step dataflow:
//   scan1(t) -> h1 -> wh -> attn -> barv[t+1] -> xg2[t+1] ; scan2(t) one step behind.
__global__ __launch_bounds__(1024) void k_mega(
    const unsigned char* __restrict__ W8,
    const unsigned short* __restrict__ xg1,
    const unsigned short* __restrict__ v16,
    const unsigned short* __restrict__ pool,
    const float* __restrict__ bhk, const float* __restrict__ W2, const float* __restrict__ b2,
    const float* __restrict__ b1, const float* __restrict__ b_ih, const float* __restrict__ b_hh,
    float* __restrict__ decv, float* __restrict__ genv,
    unsigned short* __restrict__ X){
  __shared__ __align__(16) unsigned char smem[93184];
  unsigned char*  h1f = smem;                              // 2*16*264 = 8448
  unsigned char*  h2f = smem + 8448;                       // 8448
  unsigned short* h1b = (unsigned short*)(smem + 16896);   // [16][272] bf16 h1[t]
  unsigned short* whl = (unsigned short*)(smem + 25600);   // [16][272] wh
  unsigned short* bvl = (unsigned short*)(smem + 34304);   // [16][272] barv
  unsigned short* ekl = (unsigned short*)(smem + 43008);   // [16][272] e_k
  unsigned short* xgT = (unsigned short*)(smem + 51712);   // [1024][20] xg2 gate-major
  float*          ap  = (float*)(smem + 92672);            // [64][2] attn partials

  int g = blockIdx.x;
  int tid = threadIdx.x, w = tid>>6, l = tid&63, lm = l&15, q = l>>4;
  int j = w*16 + lm;

  // ---- prologue: zero h-state, load e_k/barv0, W_hh frags, u GEMM, xg2[0] ----
  for (int i=tid;i<4224;i+=1024) ((unsigned*)smem)[i] = 0;   // h1f + h2f
  {
    int row = tid>>6, c4 = (tid&63)*4;
    s16x4 ev = *(const s16x4*)(v16 + (size_t)(g*16+row)*Vx*Dx + c4);
    *(s16x4*)(ekl + row*BFP + c4) = ev;
    *(s16x4*)(bvl + row*BFP + c4) = ev;
  }
  long Bf[4][8];
  #pragma unroll
  for (int qq=0;qq<4;qq++){
    int n = qq*256 + j;
    #pragma unroll
    for (int kk=0;kk<8;kk++)
      Bf[qq][kk] = *(const long*)(W8 + (size_t)n*256 + kk*32 + q*8);
  }
  lds_barrier();
  xg2_gemm(bvl, pool, b_ih, b_hh, xgT, w, lm, q);            // xg2[0] from barv[0]=e_k
  f32x4 uacc;                                                // u = e_k@W1_left^T + b1 (waves 0..3)
  if (w < 4){
    int n = w*16 + lm;
    float bz = b1[n];
    uacc = (f32x4){bz,bz,bz,bz};
    #pragma unroll
    for (int kk=0;kk<8;kk++){
      s16x8 afr = *(const s16x8*)(ekl + lm*BFP + kk*32 + q*8);
      s16x8 bfr = *(const s16x8*)(pool + PW_1 + (size_t)n*512 + kk*32 + q*8);
      uacc = mfma_bf16(afr, bfr, uacc);
    }
  }
  const unsigned short* xgb = xg1 + (size_t)g*16384 + q*4;
  s16x4 xc1[4], xn1[4];
  #pragma unroll
  for (int qq=0;qq<4;qq++) xc1[qq] = *(const s16x4*)(xgb + (qq*256+j)*16);
  lds_barrier();

  float cst1[4] = {0,0,0,0}, cst2[4] = {0,0,0,0};
  const unsigned char* hr1 = h1f + lm*HPB + q*8;
  const unsigned char* hr2 = h2f + lm*HPB + q*8;

  #pragma unroll 1
  for (int t=0;t<Vx;t++){
    // ---- A: addend init + dual-scan MFMA + xg1 prefetch ----
    f32x4 A1[4], A2[4];
    #pragma unroll
    for (int qq=0;qq<4;qq++){
      s16x4 xv = *(const s16x4*)(xgT + (qq*256+j)*XGP + q*4);
      #pragma unroll
      for (int r=0;r<4;r++){
        A1[qq][r] = bf2f((unsigned short)xc1[qq][r]);
        A2[qq][r] = bf2f((unsigned short)xv[r]);
      }
    }
    if (t < Vx-1){
      #pragma unroll
      for (int qq=0;qq<4;qq++)
        xn1[qq] = *(const s16x4*)(xgb + (size_t)(t+1)*131072 + (qq*256+j)*16);
    }
    const unsigned char* hb1 = hr1 + (t&1)*4224;
    const unsigned char* hb2 = hr2 + (t&1)*4224;
    #pragma unroll
    for (int kk=0;kk<8;kk++){
      long af = *(const long*)(hb1 + kk*32);
      A1[0] = mfma_fp8(af, Bf[0][kk], A1[0]);
      A1[1] = mfma_fp8(af, Bf[1][kk], A1[1]);
      A1[2] = mfma_fp8(af, Bf[2][kk], A1[2]);
      A1[3] = mfma_fp8(af, Bf[3][kk], A1[3]);
    }
    #pragma unroll
    for (int kk=0;kk<8;kk++){
      long af = *(const long*)(hb2 + kk*32);
      A2[0] = mfma_fp8(af, Bf[0][kk], A2[0]);
      A2[1] = mfma_fp8(af, Bf[1][kk], A2[1]);
      A2[2] = mfma_fp8(af, Bf[2][kk], A2[2]);
      A2[3] = mfma_fp8(af, Bf[3][kk], A2[3]);
    }
    // ---- B: activations, write next h state ----
    float hv1[4], hv2[4];
    lstm_act(A1, cst1, hv1);
    lstm_act(A2, cst2, hv2);
    store_h_fp8(h1f + ((t+1)&1)*4224 + j, q, hv1);
    store_h_fp8(h2f + ((t+1)&1)*4224 + j, q, hv2);
    #pragma unroll
    for (int r=0;r<4;r++) h1b[(q*4+r)*BFP + j] = f2bf(hv1[r]);
    if (t == Vx-1){
      #pragma unroll
      for (int r=0;r<4;r++){
        X[(size_t)(g*16 + q*4 + r)*256 + j]       = f2bf(hv1[r]);
        X[(size_t)(128 + g*16 + q*4 + r)*256 + j] = f2bf(hv2[r]);
      }
    }
    lds_barrier();
    if (t < Vx-1){
      // ---- C1: wh = h1@Whk^T + bhk (wave w -> n-tile w) ----
      {
        int n = w*16 + lm;
        float bz = bhk[n];
        f32x4 wa = (f32x4){bz,bz,bz,bz};
        #pragma unroll
        for (int kk=0;kk<8;kk++){
          s16x8 afr = *(const s16x8*)(h1b + lm*BFP + kk*32 + q*8);
          s16x8 bfr = *(const s16x8*)(pool + PW_HK + (size_t)n*256 + kk*32 + q*8);
          wa = mfma_bf16(afr, bfr, wa);
        }
        #pragma unroll
        for (int r=0;r<4;r++) whl[(q*4+r)*BFP + n] = f2bf(wa[r]);
      }
      lds_barrier();
      // ---- C2: attn logits partial (waves 0..3) ----
      if (w < 4){
        int n = w*16 + lm;
        f32x4 ta = uacc;
        #pragma unroll
        for (int kk=0;kk<8;kk++){
          s16x8 afr = *(const s16x8*)(whl + lm*BFP + kk*32 + q*8);
          s16x8 bfr = *(const s16x8*)(pool + PW_1 + (size_t)n*512 + 256 + kk*32 + q*8);
          ta = mfma_bf16(afr, bfr, ta);
        }
        float w2a = W2[n], w2b = W2[64+n];
        float p0a[4], p1a[4];
        #pragma unroll
        for (int r=0;r<4;r++){
          float z = tanh_(ta[r]);
          p0a[r] = z*w2a; p1a[r] = z*w2b;
        }
        #pragma unroll
        for (int s=1;s<16;s<<=1){
          #pragma unroll
          for (int r=0;r<4;r++){
            p0a[r] += __shfl_xor(p0a[r], s, 16);
            p1a[r] += __shfl_xor(p1a[r], s, 16);
          }
        }
        if (lm == 0){
          #pragma unroll
          for (int r=0;r<4;r++){
            ap[(w*16 + q*4 + r)*2    ] = p0a[r];
            ap[(w*16 + q*4 + r)*2 + 1] = p1a[r];
          }
        }
      }
      lds_barrier();
      // ---- C3: alpha + mix -> decv/genv/barv[t+1] ----
      {
        int row = tid>>6, c4 = (tid&63)*4;
        float g0 = b2[0], g1 = b2[1];
        #pragma unroll
        for (int w4=0;w4<4;w4++){
          g0 += ap[(w4*16+row)*2];
          g1 += ap[(w4*16+row)*2+1];
        }
        float al0 = frcp_(1.f + fexp2_(1.4426950408889634f*(g1-g0)));
        float al1 = 1.f - al0;
        s16x4 e4 = *(const s16x4*)(ekl + row*BFP + c4);
        s16x4 h4 = *(const s16x4*)(whl + row*BFP + c4);
        f32x4 ov; s16x4 o16;
        #pragma unroll
        for (int i=0;i<4;i++){
          float o = al0*bf2f((unsigned short)e4[i]) + al1*bf2f((unsigned short)h4[i]);
          ov[i] = o; o16[i] = (short)f2bf(o);
        }
        size_t ob = ((size_t)(g*16+row)*Vx + (t+1))*Dx + c4;
        *(f32x4*)(decv + ob) = ov;
        *(f32x4*)(genv + ob) = ov;
        *(s16x4*)(bvl + row*BFP + c4) = o16;
      }
      lds_barrier();
      // ---- D: xg2[t+1] = barv[t+1]@W_ih^T + biases ----
      xg2_gemm(bvl, pool, b_ih, b_hh, xgT, w, lm, q);
      lds_barrier();
      #pragma unroll
      for (int qq=0;qq<4;qq++) xc1[qq] = xn1[qq];
    }
  }
}

// ---------- final logits: out = y2 @ CoW^T + Cob ----------
__global__ void k_out(const unsigned short* __restrict__ y2, const unsigned short* __restrict__ CoW16,
                      const float* __restrict__ Cob, float* __restrict__ out){
  int tid = blockIdx.x*256 + threadIdx.x;
  int m = tid>>1, n = tid&1;
  const s16x8* yr = (const s16x8*)(y2 + (size_t)m*512);
  const s16x8* wr = (const s16x8*)(CoW16 + (size_t)n*512);
  float a = Cob[n];
  for (int kk=0;kk<64;kk++){
    s16x8 yv = yr[kk], ww = wr[kk];
    #pragma unroll
    for (int jj=0;jj<8;jj++) a += bf2f((unsigned short)yv[jj])*bf2f((unsigned short)ww[jj]);
  }
  int base = (m < 128) ? (OFF_OG + m*2) : (OFF_FAKE + (m-128)*2);
  out[base + n] = a;
}

// ---------- launch ----------
extern "C" void kernel_launch(void* const* d_in, const int* in_sizes, int n_in,
                              void* d_out, int out_size, void* d_ws, size_t ws_size,
                              hipStream_t stream) {
  const int*   seqs  = (const int*)d_in[0];
  const float* sts   = (const float*)d_in[3];
  const int*   label = (const int*)d_in[5];
  const float* emb   = (const float*)d_in[6];
  const float* W_ih  = (const float*)d_in[7];
  const float* W_hh  = (const float*)d_in[8];
  const float* b_ih  = (const float*)d_in[9];
  const float* b_hh  = (const float*)d_in[10];
  const float* Whk   = (const float*)d_in[11];
  const float* bhk   = (const float*)d_in[12];
  const float* W1    = (const float*)d_in[13];
  const float* b1    = (const float*)d_in[14];
  const float* W2    = (const float*)d_in[15];
  const float* b2    = (const float*)d_in[16];
  const float* C1b   = (const float*)d_in[18];
  const float* C2b   = (const float*)d_in[20];
  const float* Cob   = (const float*)d_in[22];
  float* out = (float*)d_out;

  char* ws = (char*)d_ws;
  unsigned short* v16    = (unsigned short*)(ws + 0);            //  4 MiB [b][t][d] bf16
  unsigned short* xg1    = (unsigned short*)(ws + (4<<20));      // 16 MiB [t][g][n][16]
  unsigned short* X      = (unsigned short*)(ws + (20<<20));     // 128 KiB [256][256] bf16
  unsigned short* emb16  = (unsigned short*)(ws + (21<<20));     // 10.25 MiB
  unsigned short* pool   = (unsigned short*)(ws + (33<<20));     // 2.82 MiB
  unsigned char*  whh8   = (unsigned char*)(ws + (36<<20));      // 256 KiB
  unsigned short* y1     = xg1;                                  // overlay (xg1 dead post-mega)
  unsigned short* y2     = xg1 + 262144;

  float* decv = out + OFF_DECV;
  float* genv = out + OFF_GENV;

  k_cvt_emb<<<dim3(NVOC), dim3(256), 0, stream>>>(emb, emb16);
  k_pre<<<dim3(14725), dim3(256), 0, stream>>>(seqs, emb16, v16, decv, genv,
      W_ih, W_hh, Whk, W1, (const float*)d_in[17], (const float*)d_in[19],
      (const float*)d_in[21], pool, whh8, sts, label, out);
  k_gemm<1,1,0><<<dim3(128,4), dim3(256), 0, stream>>>(v16, pool+PW_IH, b_ih, b_hh, xg1, 256, 1024, 256.f);
  k_mega<<<dim3(8), dim3(1024), 0, stream>>>(whh8, xg1, v16, pool,
      bhk, W2, b2, b1, b_ih, b_hh, decv, genv, X);
  k_gemm<0,0,1><<<dim3(4,4), dim3(256), 0, stream>>>(X, pool+PC_1, C1b, nullptr, y1, 256, 1024, 1.f);
  k_gemm<0,0,1><<<dim3(4,2), dim3(256), 0, stream>>>(y1, pool+PC_2, C2b, nullptr, y2, 1024, 512, 1.f);
  k_out<<<dim3(2), dim3(256), 0, stream>>>(y2, pool+PC_O, Cob, out);
}

// Round 4
// 484.807 us; speedup vs baseline: 5.7507x; 5.7507x over previous
//
#include <hip/hip_runtime.h>

#define DEV __device__ __forceinline__

typedef float f32x4 __attribute__((ext_vector_type(4)));
typedef short s16x8 __attribute__((ext_vector_type(8)));
typedef short s16x4 __attribute__((ext_vector_type(4)));

// ---------- scalar helpers ----------
DEV unsigned short f2bf(float f){
  unsigned int u = __float_as_uint(f);
  u += 0x7fffu + ((u>>16)&1u);
  return (unsigned short)(u>>16);
}
DEV float bf2f(unsigned short h){ return __uint_as_float(((unsigned int)h)<<16); }

#if __has_builtin(__builtin_amdgcn_rcpf)
DEV float frcp_(float x){ return __builtin_amdgcn_rcpf(x); }
#else
DEV float frcp_(float x){ return 1.f/x; }
#endif
#if __has_builtin(__builtin_amdgcn_exp2f)
DEV float fexp2_(float x){ return __builtin_amdgcn_exp2f(x); }
#else
DEV float fexp2_(float x){ return exp2f(x); }
#endif

DEV float tanh_(float x){
  x = fminf(x, 30.f);
  float e = fexp2_(2.8853900817779268f*x);
  return (e-1.f)*frcp_(e+1.f);
}

// branchless f32 -> OCP e4m3fn (fallback when no HW cvt)
DEV unsigned char f2e4m3(float x){
  unsigned int u = __float_as_uint(x);
  unsigned int s = (u>>24)&0x80u;
  unsigned int mag = u & 0x7fffffffu;
  if (mag > 0x43E00000u) mag = 0x43E00000u;
  mag += 0x000FFFFFu + ((mag>>20)&1u);
  int e = (int)(mag>>23) - 120;
  unsigned int m = (mag>>20)&7u;
  unsigned int r = (e<=0) ? 0u : (((unsigned)e<<3)|m);
  return (unsigned char)(s|r);
}

DEV f32x4 mfma_bf16(s16x8 a, s16x8 b, f32x4 c){
  return __builtin_amdgcn_mfma_f32_16x16x32_bf16(a,b,c,0,0,0);
}
DEV f32x4 mfma_fp8(long a, long b, f32x4 c){
  return __builtin_amdgcn_mfma_f32_16x16x32_fp8_fp8(a,b,c,0,0,0);
}

// LDS-only barrier (no vmcnt drain)
DEV void lds_barrier(){
  asm volatile("s_waitcnt lgkmcnt(0)\n\ts_barrier" ::: "memory");
}

// ---------- fence-free sync primitives ----------
// All cross-block data moves via RELAXED agent-scope atomics (write-through to
// the coherence point, bypass L2). Flags are relaxed too; ordering comes from
// vmcnt(0) drain (inside __syncthreads) between data stores and flag store.
// No release (no buffer_wbl2), no acquire (no L2 invalidate) anywhere.
DEV unsigned aload_rlx(unsigned* p){
  return __hip_atomic_load(p, __ATOMIC_RELAXED, __HIP_MEMORY_SCOPE_AGENT);
}
DEV void astore_rlx(unsigned* p, unsigned v){
  __hip_atomic_store(p, v, __ATOMIC_RELAXED, __HIP_MEMORY_SCOPE_AGENT);
}
DEV void aadd_rlx(unsigned* p, unsigned v){
  __hip_atomic_fetch_add(p, v, __ATOMIC_RELAXED, __HIP_MEMORY_SCOPE_AGENT);
}
DEV void spin_rlx(unsigned* p, unsigned tgt){
  while (aload_rlx(p) < tgt) __builtin_amdgcn_s_sleep(2);
  asm volatile("" ::: "memory");
}
DEV void block_wait(unsigned* p, unsigned tgt){
  if (threadIdx.x == 0) spin_rlx(p, tgt);
  __syncthreads();
}
DEV s16x4 aload64(const unsigned short* p){
  unsigned long long v = __hip_atomic_load((unsigned long long*)(void*)p,
      __ATOMIC_RELAXED, __HIP_MEMORY_SCOPE_AGENT);
  union { unsigned long long u; s16x4 s; } c; c.u = v; return c.s;
}
DEV void astore64(unsigned short* p, s16x4 v){
  union { s16x4 s; unsigned long long u; } c; c.s = v;
  __hip_atomic_store((unsigned long long*)(void*)p, c.u,
      __ATOMIC_RELAXED, __HIP_MEMORY_SCOPE_AGENT);
}
DEV s16x8 aload128(const unsigned short* p){
  s16x4 a = aload64(p), b = aload64(p+4);
  s16x8 r;
  r[0]=a[0]; r[1]=a[1]; r[2]=a[2]; r[3]=a[3];
  r[4]=b[0]; r[5]=b[1]; r[6]=b[2]; r[7]=b[3];
  return r;
}
DEV float aloadf(const float* p){
  return __hip_atomic_load((float*)(void*)p, __ATOMIC_RELAXED, __HIP_MEMORY_SCOPE_AGENT);
}
DEV void astoref(float* p, float v){
  __hip_atomic_store(p, v, __ATOMIC_RELAXED, __HIP_MEMORY_SCOPE_AGENT);
}
DEV void vm_drain(){ asm volatile("s_waitcnt vmcnt(0)" ::: "memory"); }
DEV void ntf(float* p, float v){ __builtin_nontemporal_store(v, p); }

// ---------- problem constants ----------
#define Bx 128
#define Vx 64
#define Sx 40
#define Dx 256
#define Hx 256
#define NVOC 20001

// d_out element offsets (f32)
#define OFF_OG   0
#define OFF_FAKE 256
#define OFF_DECV 512
#define OFF_GENV 2097664
#define OFF_STS  4194816
#define OFF_LBL  4203008

// bf16 weight-pool element offsets
#define PW_IH  0
#define PW_HH  262144
#define PW_HK  524288
#define PW_1   589824
#define PC_1   622592
#define PC_2   884736
#define PC_O   1409024
#define P_TOT  1410048

#define HPB 264      // scan LDS fp8 row pitch (bytes)
#define BFP 272      // scan h1b LDS pitch (shorts)
#define WHP 272      // worker wh/barv LDS pitch (shorts)

// flag slots (ints): one per 128-B line
#define FCT(t) ((t)*32)
#define FXG(t) (2048 + (t)*32)
#define FUC    4096
#define FTOT   4224

// ---------- K-1: emb f32 -> bf16 ----------
__global__ void k_cvt_emb(const float* __restrict__ emb, unsigned short* __restrict__ emb16){
  size_t i = (size_t)blockIdx.x*256 + threadIdx.x;
  emb16[i] = f2bf(emb[i]);
}

// ---------- PRE: embed + weight cvt + flags/passthrough ----------
__global__ void k_pre(const int* __restrict__ seqs, const unsigned short* __restrict__ emb16,
                      unsigned short* __restrict__ v16,
                      float* __restrict__ decv, float* __restrict__ genv,
                      const float* __restrict__ W_ih, const float* __restrict__ Whh,
                      const float* __restrict__ Whk, const float* __restrict__ W1,
                      const float* __restrict__ C1W, const float* __restrict__ C2W,
                      const float* __restrict__ CoW,
                      unsigned short* __restrict__ pool, unsigned char* __restrict__ whh8,
                      const float* __restrict__ sts, const int* __restrict__ label,
                      float* __restrict__ out, unsigned* __restrict__ flags){
  int bx = blockIdx.x, tid = threadIdx.x;
  if (bx < 8192){                       // embed: v = sum_s relu(emb[idx])
    int bt = bx, d = tid;
    const int* sp = seqs + (size_t)bt*Sx;
    float acc = 0.f;
    #pragma unroll 8
    for (int s=0;s<Sx;s++) acc += fmaxf(bf2f(emb16[(size_t)sp[s]*Dx + d]), 0.f);
    size_t o = (size_t)bt*Dx + d;
    v16[o] = f2bf(acc);
    if ((bt & 63) == 0){ decv[o] = acc; genv[o] = acc; }
    return;
  }
  if (bx < 14724){                      // weight conversions
    int i = (bx-8192)*256 + tid;
    if (i < P_TOT){
      float v;
      if      (i < PW_HH) v = W_ih[i - PW_IH];
      else if (i < PW_HK) v = Whh [i - PW_HH];
      else if (i < PW_1 ) v = Whk [i - PW_HK];
      else if (i < PC_1 ) v = W1  [i - PW_1 ];
      else if (i < PC_2 ) v = C1W [i - PC_1 ];
      else if (i < PC_O ) v = C2W [i - PC_2 ];
      else                v = CoW [i - PC_O ];
      pool[i] = f2bf(v);
    } else if (i < P_TOT + 262144){
      whh8[i - P_TOT] = f2e4m3(16.f*Whh[i - P_TOT]);
    }
    return;
  }
  // misc block: flags init + passthrough outputs
  for (int i=tid;i<FTOT;i+=256) flags[i] = 0u;
  for (int i=tid;i<Bx*Vx;i+=256) out[OFF_STS + i] = sts[i];
  if (tid < Bx) out[OFF_LBL + tid] = (float)label[tid];
}

// ---------- generic MFMA GEMM (xg1 + classifier layers) ----------
template<int MODE_A, int MODE_C, int RELU>
__global__ void k_gemm(const unsigned short* __restrict__ A, const unsigned short* __restrict__ Bw,
                       const float* __restrict__ bias1, const float* __restrict__ bias2,
                       unsigned short* __restrict__ C, int K, int Ntot, float scale){
  int tid = threadIdx.x, w = tid>>6, l = tid&63, lm = l&15, q = l>>4;
  int m0 = blockIdx.x*64;
  int n0 = blockIdx.y*256 + w*64;
  f32x4 acc[4][4];
  #pragma unroll
  for (int nt=0;nt<4;nt++){
    int n = n0 + nt*16 + lm;
    float bz = bias1 ? bias1[n] : 0.f;
    if (bias2) bz += bias2[n];
    #pragma unroll
    for (int mt=0;mt<4;mt++) acc[mt][nt] = (f32x4){bz,bz,bz,bz};
  }
  const s16x8* Arow[4];
  #pragma unroll
  for (int mt=0;mt<4;mt++){
    int m = m0 + mt*16 + lm;
    size_t off = (MODE_A==0) ? (size_t)m*K : ((size_t)(m&127)*Vx + (m>>7))*(size_t)K;
    Arow[mt] = (const s16x8*)(A + off);
  }
  int kkn = K/32;
  for (int kk=0; kk<kkn; kk++){
    s16x8 bfr[4];
    #pragma unroll
    for (int nt=0;nt<4;nt++){
      int n = n0 + nt*16 + lm;
      bfr[nt] = *(const s16x8*)(Bw + (size_t)n*K + kk*32 + q*8);
    }
    #pragma unroll
    for (int mt=0;mt<4;mt++){
      s16x8 afr = Arow[mt][kk*4 + q];
      #pragma unroll
      for (int nt=0;nt<4;nt++)
        acc[mt][nt] = mfma_bf16(afr, bfr[nt], acc[mt][nt]);
    }
  }
  #pragma unroll
  for (int mt=0;mt<4;mt++){
    int mbase = m0 + mt*16 + q*4;
    #pragma unroll
    for (int nt=0;nt<4;nt++){
      int n = n0 + nt*16 + lm;
      if (MODE_C==0){
        #pragma unroll
        for (int r=0;r<4;r++){
          float val = scale*acc[mt][nt][r];
          if (RELU) val = fmaxf(val, 0.f);
          C[(size_t)(mbase+r)*Ntot + n] = f2bf(val);
        }
      } else {
        int tt = mbase>>7, bb = mbase&127;
        int gg = bb>>4;
        s16x4 sv;
        #pragma unroll
        for (int r=0;r<4;r++) sv[r] = (short)f2bf(scale*acc[mt][nt][r]);
        *(s16x4*)(C + (((size_t)tt*8 + gg)*1024 + n)*16 + (bb&15)) = sv;
      }
    }
  }
}

// ---------- LSTM gate activations (inputs scaled by 256) ----------
DEV void lstm_act(const f32x4* A, float* cst, float* hv){
  const float K1 = 1.4426950408889634f/256.f;
  #pragma unroll
  for (int r=0;r<4;r++){
    float iv = frcp_(1.f + fexp2_(-K1*A[0][r]));
    float fv = frcp_(1.f + fexp2_(-K1*A[1][r]));
    float eg = fexp2_(2.f*K1*A[2][r]);
    float gv = (eg-1.f)*frcp_(eg+1.f);
    float ov = frcp_(1.f + fexp2_(-K1*A[3][r]));
    float cv = fv*cst[r] + iv*gv;
    cst[r] = cv;
    float ec = fexp2_(2.8853900817779268f*fminf(cv,30.f));
    hv[r] = ov*(ec-1.f)*frcp_(ec+1.f);
  }
}

// store 4 h values (rows q*4+r) as fp8(16*h) at column j of next h-buffer
DEV void store_h_fp8(unsigned char* hn, int q, const float* hv){
#if __has_builtin(__builtin_amdgcn_cvt_pk_fp8_f32)
  int p01 = __builtin_amdgcn_cvt_pk_fp8_f32(16.f*hv[0], 16.f*hv[1], 0, false);
  int p23 = __builtin_amdgcn_cvt_pk_fp8_f32(16.f*hv[2], 16.f*hv[3], 0, false);
  hn[(q*4+0)*HPB] = (unsigned char)p01;
  hn[(q*4+1)*HPB] = (unsigned char)(p01>>8);
  hn[(q*4+2)*HPB] = (unsigned char)p23;
  hn[(q*4+3)*HPB] = (unsigned char)(p23>>8);
#else
  #pragma unroll
  for (int r=0;r<4;r++) hn[(q*4+r)*HPB] = f2e4m3(16.f*hv[r]);
#endif
}

// ---------- scan body (scan1 publishes h[t] via relaxed atomics; scan2 consumes xg2) ----------
template<int IS1>
DEV void scan_body(unsigned char* smem, const unsigned char* __restrict__ W8,
                   const unsigned short* __restrict__ xg, unsigned short* __restrict__ hist,
                   int g, unsigned* __restrict__ flags){
  unsigned char*  hl  = smem;                               // 2*16*264 = 8448 fp8 dbuf
  unsigned short* h1b = (unsigned short*)(smem + 8448);     // [16][272] bf16 (IS1 only)
  int tid = threadIdx.x;
  int w = tid>>6, l = tid&63, lm = l&15, q = l>>4;
  int j = w*16 + lm;
  for (int i=tid;i<8448;i+=1024) hl[i] = 0;
  long Bf[4][8];
  #pragma unroll
  for (int qq=0;qq<4;qq++){
    int n = qq*256 + j;
    #pragma unroll
    for (int kk=0;kk<8;kk++)
      Bf[qq][kk] = *(const long*)(W8 + (size_t)n*256 + kk*32 + q*8);
  }
  float cst[4] = {0.f,0.f,0.f,0.f};
  const unsigned short* xgb = xg + (size_t)g*16384 + q*4;
  s16x4 xc[4], xn[4];
  if (!IS1) block_wait(&flags[FXG(0)], 1);
  #pragma unroll
  for (int qq=0;qq<4;qq++){
    const unsigned short* p = xgb + (qq*256+j)*16;
    xc[qq] = IS1 ? *(const s16x4*)p : aload64(p);
  }
  __syncthreads();
  const unsigned char* hrd = hl + lm*HPB + q*8;
  #pragma unroll 1
  for (int t=0;t<Vx;t++){
    if (t < Vx-1){
      if (!IS1) block_wait(&flags[FXG(t+1)], 1);
      #pragma unroll
      for (int qq=0;qq<4;qq++){
        const unsigned short* p = xgb + (size_t)(t+1)*131072 + (qq*256+j)*16;
        xn[qq] = IS1 ? *(const s16x4*)p : aload64(p);
      }
    }
    const unsigned char* hb = hrd + (t&1)*4224;
    f32x4 A[4];
    #pragma unroll
    for (int qq=0;qq<4;qq++){
      #pragma unroll
      for (int r=0;r<4;r++) A[qq][r] = bf2f((unsigned short)xc[qq][r]);
    }
    #pragma unroll
    for (int kk=0;kk<8;kk++){
      long af = *(const long*)(hb + kk*32);
      A[0] = mfma_fp8(af, Bf[0][kk], A[0]);
      A[1] = mfma_fp8(af, Bf[1][kk], A[1]);
      A[2] = mfma_fp8(af, Bf[2][kk], A[2]);
      A[3] = mfma_fp8(af, Bf[3][kk], A[3]);
    }
    float hv[4];
    lstm_act(A, cst, hv);
    store_h_fp8(hl + ((t+1)&1)*4224 + j, q, hv);
    if (IS1){
      // h[t] -> LDS transpose -> one 8B relaxed atomic per thread -> flag
      #pragma unroll
      for (int r=0;r<4;r++) h1b[(q*4+r)*BFP + j] = f2bf(hv[r]);
      lds_barrier();
      {
        int row = tid>>6, c4 = (tid&63)*4;
        s16x4 hx = *(const s16x4*)(h1b + row*BFP + c4);
        astore64(hist + ((size_t)t*Bx + g*16 + row)*Hx + c4, hx);
      }
      vm_drain();
      __syncthreads();
      if (tid == 0) aadd_rlx(&flags[FCT(t)], 1);
    } else {
      if (t == Vx-1){
        #pragma unroll
        for (int r=0;r<4;r++)
          hist[(size_t)(g*16 + q*4 + r)*Hx + j] = f2bf(hv[r]);
      }
      lds_barrier();
    }
    #pragma unroll
    for (int qq=0;qq<4;qq++) xc[qq] = xn[qq];
  }
}

// xg2 tile GEMM for step `tile`: A rows from LDS (barv) or global v16 (e_k)
template<int ALDS>
DEV void xg2_tile(const unsigned short* Ab, const unsigned short* __restrict__ pool,
                  const float* __restrict__ b_ih, const float* __restrict__ b_hh,
                  unsigned short* __restrict__ xg2, int tile, int w, int lm, int q){
  int mh = (w&1)*64, nb = (w>>1)*128;
  #pragma unroll 1
  for (int sc=0; sc<4; sc++){
    int n0 = nb + sc*32;
    f32x4 acc[4][2];
    #pragma unroll
    for (int nt=0;nt<2;nt++){
      int n = n0 + nt*16 + lm;
      float bz = b_ih[n] + b_hh[n];
      #pragma unroll
      for (int mt=0;mt<4;mt++) acc[mt][nt] = (f32x4){bz,bz,bz,bz};
    }
    #pragma unroll
    for (int kk=0;kk<8;kk++){
      s16x8 bfr[2];
      #pragma unroll
      for (int nt=0;nt<2;nt++){
        int n = n0 + nt*16 + lm;
        bfr[nt] = *(const s16x8*)(pool + PW_IH + (size_t)n*256 + kk*32 + q*8);
      }
      #pragma unroll
      for (int mt=0;mt<4;mt++){
        int row = mh + mt*16 + lm;
        s16x8 afr = ALDS ? *(const s16x8*)(Ab + (size_t)row*WHP + kk*32 + q*8)
                         : *(const s16x8*)(Ab + (size_t)row*Vx*Dx + kk*32 + q*8);
        acc[mt][0] = mfma_bf16(afr, bfr[0], acc[mt][0]);
        acc[mt][1] = mfma_bf16(afr, bfr[1], acc[mt][1]);
      }
    }
    #pragma unroll
    for (int mt=0;mt<4;mt++){
      int m = mh + mt*16 + q*4;
      int gg = m>>4;
      #pragma unroll
      for (int nt=0;nt<2;nt++){
        int n = n0 + nt*16 + lm;
        s16x4 sv;
        #pragma unroll
        for (int r=0;r<4;r++) sv[r] = (short)f2bf(256.f*acc[mt][nt][r]);
        astore64(xg2 + (((size_t)tile*8 + gg)*1024 + n)*16 + (m&15), sv);
      }
    }
  }
}

// ---------- fused worker: wh -> attn -> barv(LDS, in-place) -> xg2[t+1] ----------
DEV void worker_body(unsigned short* whs, int t,
    const unsigned short* __restrict__ hist1, const unsigned short* __restrict__ v16,
    const float* __restrict__ u, const unsigned short* __restrict__ pool,
    const float* __restrict__ bhk, const float* __restrict__ W2, const float* __restrict__ b2,
    const float* __restrict__ b_ih, const float* __restrict__ b_hh,
    float* __restrict__ decv, float* __restrict__ genv,
    unsigned short* __restrict__ xg2, unsigned* __restrict__ flags){
  int tid = threadIdx.x, w = tid>>6, l = tid&63, lm = l&15, q = l>>4;
  if (t == 63){
    // xg2[0] from e_k (= v16[:,0,:]) directly; no waits
    xg2_tile<0>(v16, pool, b_ih, b_hh, xg2, 0, w, lm, q);
    vm_drain();
    __syncthreads();
    if (tid == 0) astore_rlx(&flags[FXG(0)], 1);
    return;
  }
  block_wait(&flags[FCT(t)], 8);                // scan1 step t published (relaxed)
  // ---- wh tile: 128x256, wave w -> rows (w&7)*16, cols (w>>3)*128 ----
  {
    int r0 = (w&7)*16, n0 = (w>>3)*128;
    const unsigned short* Ar = hist1 + ((size_t)t*Bx + r0 + lm)*Hx;
    f32x4 acc[8];
    #pragma unroll
    for (int nt=0;nt<8;nt++){
      float bz = bhk[n0 + nt*16 + lm];
      acc[nt] = (f32x4){bz,bz,bz,bz};
    }
    #pragma unroll
    for (int kk=0;kk<8;kk++){
      s16x8 afr = aload128(Ar + kk*32 + q*8);   // coherence-point read, no fence
      #pragma unroll
      for (int nt=0;nt<8;nt++){
        int n = n0 + nt*16 + lm;
        s16x8 bfr = *(const s16x8*)(pool + PW_HK + (size_t)n*256 + kk*32 + q*8);
        acc[nt] = mfma_bf16(afr, bfr, acc[nt]);
      }
    }
    #pragma unroll
    for (int nt=0;nt<8;nt++){
      int n = n0 + nt*16 + lm, mb = r0 + q*4;
      #pragma unroll
      for (int r=0;r<4;r++) whs[(size_t)(mb+r)*WHP + n] = f2bf(acc[nt][r]);
    }
  }
  if (tid == 0) spin_rlx(&flags[FUC], 8);       // u ready (relaxed; u read via atomics)
  __syncthreads();                              // + orders whs stores
  // ---- attn on waves 0..7 (16 rows each); barv written in place over wh ----
  if (w < 8){
    int m0l = w*16;
    f32x4 a2[4];
    #pragma unroll
    for (int nt=0;nt<4;nt++){
      int n = nt*16 + lm;
      #pragma unroll
      for (int r=0;r<4;r++) a2[nt][r] = aloadf(u + (size_t)(m0l + q*4 + r)*64 + n);
    }
    #pragma unroll
    for (int kk=0;kk<8;kk++){
      s16x8 afr = *(const s16x8*)(whs + (size_t)(m0l+lm)*WHP + kk*32 + q*8);
      #pragma unroll
      for (int nt=0;nt<4;nt++){
        int n = nt*16 + lm;
        s16x8 bfr = *(const s16x8*)(pool + PW_1 + (size_t)n*512 + 256 + kk*32 + q*8);
        a2[nt] = mfma_bf16(afr, bfr, a2[nt]);
      }
    }
    float p0a[4] = {0,0,0,0}, p1a[4] = {0,0,0,0};
    #pragma unroll
    for (int nt=0;nt<4;nt++){
      int n = nt*16 + lm;
      float w2a = W2[n], w2b = W2[64+n];
      #pragma unroll
      for (int r=0;r<4;r++){
        float z = tanh_(a2[nt][r]);
        p0a[r] += z*w2a; p1a[r] += z*w2b;
      }
    }
    #pragma unroll
    for (int s=1;s<16;s<<=1){
      #pragma unroll
      for (int r=0;r<4;r++){ p0a[r] += __shfl_xor(p0a[r], s, 16); p1a[r] += __shfl_xor(p1a[r], s, 16); }
    }
    float bb0 = b2[0], bb1 = b2[1];
    int d0 = lm*16;
    #pragma unroll
    for (int r=0;r<4;r++){
      int b = m0l + q*4 + r;
      float g0 = p0a[r]+bb0, g1 = p1a[r]+bb1;
      float al0 = frcp_(1.f + fexp2_(1.4426950408889634f*(g1-g0)));
      float al1 = 1.f - al0;
      const unsigned short* ek = v16 + (size_t)b*Vx*Dx + d0;
      unsigned short* whp = whs + (size_t)b*WHP + d0;
      size_t ob = ((size_t)b*Vx + (t+1))*Dx + d0;
      #pragma unroll
      for (int c=0;c<2;c++){
        s16x8 e8 = *(const s16x8*)(ek + c*8);
        s16x8 w8 = *(const s16x8*)(whp + c*8);
        s16x8 o16;
        #pragma unroll
        for (int jj=0;jj<8;jj++){
          float o = al0*bf2f((unsigned short)e8[jj]) + al1*bf2f((unsigned short)w8[jj]);
          ntf(decv + ob + c*8 + jj, o);
          ntf(genv + ob + c*8 + jj, o);
          o16[jj] = (short)f2bf(o);
        }
        *(s16x8*)(whp + c*8) = o16;             // barv[t+1] in place
      }
    }
  }
  __syncthreads();                              // barv visible to all waves
  // ---- xg2[t+1] from LDS barv ----
  xg2_tile<1>(whs, pool, b_ih, b_hh, xg2, t+1, w, lm, q);
  vm_drain();
  __syncthreads();
  if (tid == 0) astore_rlx(&flags[FXG(t+1)], 1);
}

// ---------- MEGA: scan1 || workers || scan2 || u (fence-free protocol) ----------
__global__ __launch_bounds__(1024) void k_mega(
    const unsigned char* __restrict__ W8,
    const unsigned short* __restrict__ xg1, unsigned short* __restrict__ xg2,
    unsigned short* __restrict__ hist1, unsigned short* __restrict__ h2,
    const unsigned short* __restrict__ v16, float* __restrict__ u,
    const unsigned short* __restrict__ pool,
    const float* __restrict__ bhk, const float* __restrict__ W2, const float* __restrict__ b2,
    const float* __restrict__ b1, const float* __restrict__ b_ih, const float* __restrict__ b_hh,
    float* __restrict__ decv, float* __restrict__ genv,
    unsigned* __restrict__ flags){
  __shared__ __align__(16) unsigned char smem[69632];
  int blk = blockIdx.x;
  if (blk < 8){
    scan_body<1>(smem, W8, xg1, hist1, blk, flags);
  } else if (blk < 16){
    scan_body<0>(smem, W8, xg2, h2, blk-8, flags);
  } else if (blk < 80){
    worker_body((unsigned short*)smem, blk-16, hist1, v16, u, pool, bhk, W2, b2,
                b_ih, b_hh, decv, genv, xg2, flags);
  } else {
    // u GEMV: 8 blocks x 1024 threads = 8192 = 128 b x 64 n
    int t2 = (blk-80)*1024 + threadIdx.x;
    int b = t2>>6, n = t2&63;
    const s16x8* vr = (const s16x8*)(v16 + (size_t)b*Vx*Dx);
    const s16x8* wr = (const s16x8*)(pool + PW_1 + (size_t)n*512);
    float a = b1[n];
    for (int kk=0;kk<32;kk++){
      s16x8 x = vr[kk], ww = wr[kk];
      #pragma unroll
      for (int jj=0;jj<8;jj++) a += bf2f((unsigned short)x[jj])*bf2f((unsigned short)ww[jj]);
    }
    astoref(u + t2, a);
    vm_drain();
    __syncthreads();
    if (threadIdx.x == 0) aadd_rlx(&flags[FUC], 1);
  }
}

// ---------- final logits: out = y2 @ CoW^T + Cob ----------
__global__ void k_out(const unsigned short* __restrict__ y2, const unsigned short* __restrict__ CoW16,
                      const float* __restrict__ Cob, float* __restrict__ out){
  int tid = blockIdx.x*256 + threadIdx.x;
  int m = tid>>1, n = tid&1;
  const s16x8* yr = (const s16x8*)(y2 + (size_t)m*512);
  const s16x8* wr = (const s16x8*)(CoW16 + (size_t)n*512);
  float a = Cob[n];
  for (int kk=0;kk<64;kk++){
    s16x8 yv = yr[kk], ww = wr[kk];
    #pragma unroll
    for (int jj=0;jj<8;jj++) a += bf2f((unsigned short)yv[jj])*bf2f((unsigned short)ww[jj]);
  }
  int base = (m < 128) ? (OFF_OG + m*2) : (OFF_FAKE + (m-128)*2);
  out[base + n] = a;
}

// ---------- launch ----------
extern "C" void kernel_launch(void* const* d_in, const int* in_sizes, int n_in,
                              void* d_out, int out_size, void* d_ws, size_t ws_size,
                              hipStream_t stream) {
  const int*   seqs  = (const int*)d_in[0];
  const float* sts   = (const float*)d_in[3];
  const int*   label = (const int*)d_in[5];
  const float* emb   = (const float*)d_in[6];
  const float* W_ih  = (const float*)d_in[7];
  const float* W_hh  = (const float*)d_in[8];
  const float* b_ih  = (const float*)d_in[9];
  const float* b_hh  = (const float*)d_in[10];
  const float* Whk   = (const float*)d_in[11];
  const float* bhk   = (const float*)d_in[12];
  const float* W1    = (const float*)d_in[13];
  const float* b1    = (const float*)d_in[14];
  const float* W2    = (const float*)d_in[15];
  const float* b2    = (const float*)d_in[16];
  const float* C1b   = (const float*)d_in[18];
  const float* C2b   = (const float*)d_in[20];
  const float* Cob   = (const float*)d_in[22];
  float* out = (float*)d_out;

  char* ws = (char*)d_ws;
  unsigned short* v16    = (unsigned short*)(ws + 0);            //  4 MiB [b][t][d] bf16
  unsigned short* xg1    = (unsigned short*)(ws + (4<<20));      // 16 MiB [t][g][n][16]
  unsigned short* hist1  = (unsigned short*)(ws + (20<<20));     //  4 MiB [t][b][j] + 64K h2
  unsigned short* xg2    = (unsigned short*)(ws + (25<<20));     // 16 MiB [t][g][n][16]
  unsigned short* emb16  = xg2;                                  // overlay: dead before mega
  float*          u      = (float*)(ws + (41<<20));              // 32 KiB
  unsigned char*  whh8   = (unsigned char*)(ws + (41<<20) + (64<<10));   // 256 KiB
  unsigned*       flags  = (unsigned*)(ws + (41<<20) + (384<<10));       // 16.5 KiB
  unsigned short* pool   = (unsigned short*)(ws + (42<<20));     // 2.82 MiB
  unsigned short* y1     = xg1;                                  // overlay (xg1 dead post-mega)
  unsigned short* y2     = xg1 + 262144;

  unsigned short* h2 = hist1 + (size_t)Vx*Bx*Hx;
  unsigned short* X  = hist1 + (size_t)(Vx-1)*Bx*Hx;   // [256][256]: h1[63] ; h2

  float* decv = out + OFF_DECV;
  float* genv = out + OFF_GENV;

  k_cvt_emb<<<dim3(NVOC), dim3(256), 0, stream>>>(emb, emb16);
  k_pre<<<dim3(14725), dim3(256), 0, stream>>>(seqs, emb16, v16, decv, genv,
      W_ih, W_hh, Whk, W1, (const float*)d_in[17], (const float*)d_in[19],
      (const float*)d_in[21], pool, whh8, sts, label, out, flags);
  k_gemm<1,1,0><<<dim3(128,4), dim3(256), 0, stream>>>(v16, pool+PW_IH, b_ih, b_hh, xg1, 256, 1024, 256.f);
  k_mega<<<dim3(88), dim3(1024), 0, stream>>>(whh8, xg1, xg2, hist1, h2, v16, u, pool,
      bhk, W2, b2, b1, b_ih, b_hh, decv, genv, flags);
  k_gemm<0,0,1><<<dim3(4,4), dim3(256), 0, stream>>>(X, pool+PC_1, C1b, nullptr, y1, 256, 1024, 1.f);
  k_gemm<0,0,1><<<dim3(4,2), dim3(256), 0, stream>>>(y1, pool+PC_2, C2b, nullptr, y2, 1024, 512, 1.f);
  k_out<<<dim3(2), dim3(256), 0, stream>>>(y2, pool+PC_O, Cob, out);
}